// Round 2
// baseline (139.928 us; speedup 1.0000x reference)
//
#include <hip/hip_runtime.h>
#include <stdint.h>

// Problem constants
#define D    10000   // hypervector dimensions
#define P    784     // pixels
#define B    32      // batch
#define NL   1000    // levels
#define NC   10      // classes

#define ROWW 320           // padded words per packed row (320*32 = 10240 bits >= 10000)
#define ROWB (ROWW * 4)    // 1280 bytes per packed row
#define NW   313           // valid words (ceil(10000/32))
#define CHUNKS 8
#define PLEN  98           // P / CHUNKS
#define PLANES 7           // counts up to 98 < 128

// ws layout (bytes)
#define OFFS_OFF  0
#define LVL_OFF   (B * P * 4)                       // 100352
#define POS_OFF   (LVL_OFF + NL * ROWB)             // +1,280,000
#define PART_OFF  (POS_OFF + P * ROWB)              // +1,003,520
// part size: B*CHUNKS*PLANES*ROWW*4 = 2,293,760 ; total ws ~4.47 MB

// ---------------- kernel 1: idx -> level-row byte offsets, zero d_out ----------------
__global__ void k_idx(const float* __restrict__ x, int* __restrict__ offs,
                      float* __restrict__ out) {
    int i = blockIdx.x * 256 + threadIdx.x;
    if (i < B * P) {
        float v = rintf(x[i] * 999.0f);          // round-half-even == jnp.round
        v = fminf(fmaxf(v, 0.0f), 999.0f);
        offs[i] = (int)v * ROWB;                 // byte offset of packed level row
    }
    if (i < B * NC) out[i] = 0.0f;               // zero logits (atomics later)
}

// ---------------- kernel 2: pack sign bits of level & pos (bit=1 means -1) ----------
__global__ void k_pack(const float* __restrict__ lvl, const float* __restrict__ pos,
                       uint32_t* __restrict__ lvl_b, uint32_t* __restrict__ pos_b) {
    int bx  = blockIdx.x;
    int row = bx / 40;            // 40 blocks of 256 threads cover 10240 slots per row
    int seg = bx % 40;
    int d   = seg * 256 + threadIdx.x;
    const float* src; uint32_t* dst;
    if (row < NL) { src = lvl + (size_t)row * D;        dst = lvl_b + (size_t)row * ROWW; }
    else          { src = pos + (size_t)(row - NL) * D; dst = pos_b + (size_t)(row - NL) * ROWW; }
    float v = (d < D) ? src[d] : 1.0f;           // pad bits -> 0
    unsigned long long m = __ballot(v < 0.0f);   // bit i = lane i sign
    if ((threadIdx.x & 63) == 0) {
        // d is a multiple of 64 here -> word index even -> 8B aligned
        *(uint2*)(dst + (d >> 5)) = make_uint2((uint32_t)m, (uint32_t)(m >> 32));
    }
}

// ---------------- kernel 3: bind (XOR) + bundle (bit-sliced popcount) ---------------
// block = 64 threads (one wave), grid = (5 word-segs, CHUNKS, B)
__global__ __launch_bounds__(64) void k_bind(const int* __restrict__ offs,
                                             const uint32_t* __restrict__ lvl_b,
                                             const uint32_t* __restrict__ pos_b,
                                             uint32_t* __restrict__ part) {
    int b = blockIdx.z, c = blockIdx.y;
    int w = blockIdx.x * 64 + threadIdx.x;       // word index, [0,320)
    const int* po = offs + b * P + c * PLEN;     // block-uniform -> scalar loads
    const uint32_t* pb = pos_b + (size_t)(c * PLEN) * ROWW + w;
    const char* lb = (const char*)lvl_b;
    int wb = w << 2;

    uint32_t pl[PLANES];
    #pragma unroll
    for (int k = 0; k < PLANES; k++) pl[k] = 0;

    #pragma unroll 7
    for (int i = 0; i < PLEN; i += 2) {
        int o0 = po[i], o1 = po[i + 1];
        uint32_t l0 = *(const uint32_t*)(lb + o0 + wb);
        uint32_t l1 = *(const uint32_t*)(lb + o1 + wb);
        uint32_t x0 = l0 ^ pb[(size_t)i * ROWW];
        uint32_t x1 = l1 ^ pb[(size_t)(i + 1) * ROWW];
        // CSA: add x0+x1 into the bit-sliced counter
        uint32_t t  = x0 ^ x1;
        uint32_t cr = (x0 & x1) | (pl[0] & t);   // weight-2 carry
        pl[0] ^= t;
        #pragma unroll
        for (int k = 1; k < PLANES; k++) { uint32_t tt = pl[k] & cr; pl[k] ^= cr; cr = tt; }
    }
    uint32_t* pp = part + (size_t)((b * CHUNKS + c) * PLANES) * ROWW + w;
    #pragma unroll
    for (int k = 0; k < PLANES; k++) pp[(size_t)k * ROWW] = pl[k];
}

// ---------------- kernel 4: merge chunks, sign, classify, reduce --------------------
template <int N>
__device__ inline void bsadd(const uint32_t* a, const uint32_t* b, uint32_t* s) {
    uint32_t cin = 0;
    #pragma unroll
    for (int k = 0; k < N; k++) {
        uint32_t t = a[k] ^ b[k];
        s[k] = t ^ cin;
        cin  = (a[k] & b[k]) | (cin & t);
    }
    s[N] = cin;
}

__global__ __launch_bounds__(64) void k_cls(const uint32_t* __restrict__ part,
                                            const float* __restrict__ cw,
                                            float* __restrict__ out) {
    int b = blockIdx.y;
    int w = blockIdx.x * 64 + threadIdx.x;       // [0,320)
    float acc[NC];
    #pragma unroll
    for (int c = 0; c < NC; c++) acc[c] = 0.0f;

    if (w < NW) {
        uint32_t ch[CHUNKS][PLANES];
        #pragma unroll
        for (int c = 0; c < CHUNKS; c++)
            #pragma unroll
            for (int k = 0; k < PLANES; k++)
                ch[c][k] = part[(size_t)((b * CHUNKS + c) * PLANES + k) * ROWW + w];

        uint32_t s01[8], s23[8], s45[8], s67[8], t0[9], t1[9], s[10];
        bsadd<7>(ch[0], ch[1], s01);
        bsadd<7>(ch[2], ch[3], s23);
        bsadd<7>(ch[4], ch[5], s45);
        bsadd<7>(ch[6], ch[7], s67);             // <-- the missing reduction (bug fix)
        bsadd<8>(s01, s23, t0);
        bsadd<8>(s45, s67, t1);
        bsadd<9>(t0, t1, s);
        // minus-mask: S >= 392  (S in [0,784]; carry-out of S + 632, 632 = bits {3,4,5,6,9})
        uint32_t minus = s[9] | (s[8] & s[7] & (s[3] | s[4] | s[5] | s[6]));

        float sgn[32];
        #pragma unroll
        for (int j = 0; j < 32; j++) sgn[j] = ((minus >> j) & 1u) ? -1.0f : 1.0f;

        const float* wp = cw + w * 32;
        if (w < NW - 1) {
            #pragma unroll
            for (int c = 0; c < NC; c++) {
                const float* r = wp + c * D;
                float a = 0.0f;
                #pragma unroll
                for (int j = 0; j < 32; j++) a = fmaf(sgn[j], r[j], a);
                acc[c] = a;
            }
        } else {  // word 312: only 16 valid dims (9984..9999)
            #pragma unroll
            for (int c = 0; c < NC; c++) {
                const float* r = wp + c * D;
                float a = 0.0f;
                #pragma unroll
                for (int j = 0; j < 16; j++) a = fmaf(sgn[j], r[j], a);
                acc[c] = a;
            }
        }
    }
    // wave (=block) reduction, one atomic per class
    #pragma unroll
    for (int c = 0; c < NC; c++) {
        float v = acc[c];
        for (int o = 32; o > 0; o >>= 1) v += __shfl_down(v, o, 64);
        if (threadIdx.x == 0) atomicAdd(out + b * NC + c, v);
    }
}

extern "C" void kernel_launch(void* const* d_in, const int* in_sizes, int n_in,
                              void* d_out, int out_size, void* d_ws, size_t ws_size,
                              hipStream_t stream) {
    const float* x   = (const float*)d_in[0];   // [32,1,28,28]
    const float* pos = (const float*)d_in[1];   // [784,10000]
    const float* lvl = (const float*)d_in[2];   // [1000,10000]
    const float* cw  = (const float*)d_in[3];   // [10,10000]
    float* out = (float*)d_out;                 // [32,10]

    char* ws = (char*)d_ws;
    int*       offs  = (int*)(ws + OFFS_OFF);
    uint32_t*  lvl_b = (uint32_t*)(ws + LVL_OFF);
    uint32_t*  pos_b = (uint32_t*)(ws + POS_OFF);
    uint32_t*  part  = (uint32_t*)(ws + PART_OFF);

    k_idx <<<dim3((B * P + 255) / 256), 256, 0, stream>>>(x, offs, out);
    k_pack<<<dim3((NL + P) * 40),       256, 0, stream>>>(lvl, pos, lvl_b, pos_b);
    k_bind<<<dim3(5, CHUNKS, B),         64, 0, stream>>>(offs, lvl_b, pos_b, part);
    k_cls <<<dim3(5, B),                 64, 0, stream>>>(part, cw, out);
}

// Round 3
// 127.682 us; speedup vs baseline: 1.0959x; 1.0959x over previous
//
#include <hip/hip_runtime.h>
#include <stdint.h>

// Problem constants
#define D    10000   // hypervector dimensions
#define P    784     // pixels
#define B    32      // batch
#define NL   1000    // levels
#define NC   10      // classes

#define ROWW 320           // padded words per packed row (320*32 = 10240 bits >= 10000)
#define ROWB (ROWW * 4)    // 1280 bytes per packed row
#define NW   313           // valid words (ceil(10000/32))
#define CHUNKS 8
#define PLEN  98           // P / CHUNKS
#define PLANES 7           // counts up to 98 < 128

// ws layout (bytes)
#define OFFS_OFF  0
#define LVL_OFF   (B * P * 4)                       // 100352
#define POS_OFF   (LVL_OFF + NL * ROWB)             // +1,280,000
#define PART_OFF  (POS_OFF + P * ROWB)              // +1,003,520
// part: B*CHUNKS*PLANES*ROWW*4 = 2,293,760 ; total ws ~4.47 MB

#define PACK_BPR 10        // blocks per packed row: 256 thr * 4 dims = 1024; 10*1024 = 10240

// ------- kernel 1: pack sign bits of level & pos (bit=1 means -1) + fused idx -------
__global__ void k_pack(const float* __restrict__ x,
                       const float* __restrict__ lvl, const float* __restrict__ pos,
                       int* __restrict__ offs,
                       uint32_t* __restrict__ lvl_b, uint32_t* __restrict__ pos_b) {
    int bx  = blockIdx.x;
    int row = bx / PACK_BPR;
    int seg = bx % PACK_BPR;
    int d0  = seg * 1024 + threadIdx.x * 4;          // each lane: 4 consecutive dims
    const float* src; uint32_t* dst;
    if (row < NL) { src = lvl + (size_t)row * D;        dst = lvl_b + (size_t)row * ROWW; }
    else          { src = pos + (size_t)(row - NL) * D; dst = pos_b + (size_t)(row - NL) * ROWW; }

    uint32_t nib = 0;
    if (d0 < D) {                                    // D%4==0 -> full float4 or nothing
        float4 v = *(const float4*)(src + d0);
        nib = (v.x < 0.0f ? 1u : 0u) | (v.y < 0.0f ? 2u : 0u) |
              (v.z < 0.0f ? 4u : 0u) | (v.w < 0.0f ? 8u : 0u);
    }
    int lane = threadIdx.x & 63;
    uint32_t val = nib << ((lane & 7) * 4);          // word j <- lanes 8j..8j+7
    val |= __shfl_xor(val, 1, 64);
    val |= __shfl_xor(val, 2, 64);
    val |= __shfl_xor(val, 4, 64);
    if ((lane & 7) == 0) {
        int gword = (seg * 1024 + (threadIdx.x & ~7) * 4) >> 5;
        dst[gword] = val;                            // lanes 0,8,..: consecutive words
    }

    // fused gather-offset computation: B*P = 25088 = 98 blocks * 256 threads
    if (bx < 98) {
        int i = bx * 256 + threadIdx.x;
        float v = rintf(x[i] * 999.0f);              // round-half-even == jnp.round
        v = fminf(fmaxf(v, 0.0f), 999.0f);
        offs[i] = (int)v * ROWB;                     // byte offset of packed level row
    }
}

// ------- kernel 2: bind (XOR) + bundle (bit-sliced popcount) ------------------------
// block = 64 threads (one wave), grid = (5 word-segs, CHUNKS, B)
__global__ __launch_bounds__(64) void k_bind(const int* __restrict__ offs,
                                             const uint32_t* __restrict__ lvl_b,
                                             const uint32_t* __restrict__ pos_b,
                                             uint32_t* __restrict__ part) {
    int b = blockIdx.z, c = blockIdx.y;
    int w = blockIdx.x * 64 + threadIdx.x;           // word index, [0,320)
    const int* po = offs + b * P + c * PLEN;         // block-uniform
    const uint32_t* pb = pos_b + (size_t)(c * PLEN) * ROWW + w;
    const char* lb = (const char*)lvl_b;
    int wb = w << 2;

    uint32_t pl[PLANES];
    #pragma unroll
    for (int k = 0; k < PLANES; k++) pl[k] = 0;

    #pragma unroll 7
    for (int i = 0; i < PLEN; i += 2) {
        int o0 = po[i], o1 = po[i + 1];
        uint32_t l0 = *(const uint32_t*)(lb + o0 + wb);
        uint32_t l1 = *(const uint32_t*)(lb + o1 + wb);
        uint32_t x0 = l0 ^ pb[(size_t)i * ROWW];
        uint32_t x1 = l1 ^ pb[(size_t)(i + 1) * ROWW];
        uint32_t t  = x0 ^ x1;                       // CSA full-adder into bit-planes
        uint32_t cr = (x0 & x1) | (pl[0] & t);
        pl[0] ^= t;
        #pragma unroll
        for (int k = 1; k < PLANES; k++) { uint32_t tt = pl[k] & cr; pl[k] ^= cr; cr = tt; }
    }
    uint32_t* pp = part + (size_t)((b * CHUNKS + c) * PLANES) * ROWW + w;
    #pragma unroll
    for (int k = 0; k < PLANES; k++) pp[(size_t)k * ROWW] = pl[k];
}

// ------- kernel 3: merge chunks, sign, classify, block-reduce, direct store ---------
template <int N>
__device__ inline void bsadd(const uint32_t* a, const uint32_t* b, uint32_t* s) {
    uint32_t cin = 0;
    #pragma unroll
    for (int k = 0; k < N; k++) {
        uint32_t t = a[k] ^ b[k];
        s[k] = t ^ cin;
        cin  = (a[k] & b[k]) | (cin & t);
    }
    s[N] = cin;
}

__global__ __launch_bounds__(320) void k_cls(const uint32_t* __restrict__ part,
                                             const float* __restrict__ cw,
                                             float* __restrict__ out) {
    int b = blockIdx.x;
    int w = threadIdx.x;                             // [0,320): one word per thread
    float acc[NC];
    #pragma unroll
    for (int c = 0; c < NC; c++) acc[c] = 0.0f;

    if (w < NW) {
        uint32_t ch[CHUNKS][PLANES];
        #pragma unroll
        for (int c = 0; c < CHUNKS; c++)
            #pragma unroll
            for (int k = 0; k < PLANES; k++)
                ch[c][k] = part[(size_t)((b * CHUNKS + c) * PLANES + k) * ROWW + w];

        uint32_t s01[8], s23[8], s45[8], s67[8], t0[9], t1[9], s[10];
        bsadd<7>(ch[0], ch[1], s01);
        bsadd<7>(ch[2], ch[3], s23);
        bsadd<7>(ch[4], ch[5], s45);
        bsadd<7>(ch[6], ch[7], s67);
        bsadd<8>(s01, s23, t0);
        bsadd<8>(s45, s67, t1);
        bsadd<9>(t0, t1, s);
        // minus-mask: S >= 392  (carry-out of S + 632; 632 = bits {3,4,5,6,9})
        uint32_t minus = s[9] | (s[8] & s[7] & (s[3] | s[4] | s[5] | s[6]));

        float sgn[32];
        #pragma unroll
        for (int j = 0; j < 32; j++) sgn[j] = ((minus >> j) & 1u) ? -1.0f : 1.0f;

        const float* wp = cw + w * 32;
        int lim = (w < NW - 1) ? 32 : 16;            // word 312: dims 9984..9999
        if (lim == 32) {
            #pragma unroll
            for (int c = 0; c < NC; c++) {
                const float* r = wp + c * D;
                float a = 0.0f;
                #pragma unroll
                for (int j = 0; j < 32; j++) a = fmaf(sgn[j], r[j], a);
                acc[c] = a;
            }
        } else {
            #pragma unroll
            for (int c = 0; c < NC; c++) {
                const float* r = wp + c * D;
                float a = 0.0f;
                #pragma unroll
                for (int j = 0; j < 16; j++) a = fmaf(sgn[j], r[j], a);
                acc[c] = a;
            }
        }
    }

    // block reduction: per-wave shuffle -> LDS -> wave 0 sums 5 partials, direct store
    __shared__ float red[5][NC];
    int wave = threadIdx.x >> 6, lane = threadIdx.x & 63;
    #pragma unroll
    for (int c = 0; c < NC; c++) {
        float v = acc[c];
        for (int o = 32; o > 0; o >>= 1) v += __shfl_down(v, o, 64);
        if (lane == 0) red[wave][c] = v;
    }
    __syncthreads();
    if (threadIdx.x < NC) {
        float ssum = red[0][threadIdx.x] + red[1][threadIdx.x] + red[2][threadIdx.x]
                   + red[3][threadIdx.x] + red[4][threadIdx.x];
        out[b * NC + threadIdx.x] = ssum;            // no atomics, no pre-zeroing
    }
}

extern "C" void kernel_launch(void* const* d_in, const int* in_sizes, int n_in,
                              void* d_out, int out_size, void* d_ws, size_t ws_size,
                              hipStream_t stream) {
    const float* x   = (const float*)d_in[0];   // [32,1,28,28]
    const float* pos = (const float*)d_in[1];   // [784,10000]
    const float* lvl = (const float*)d_in[2];   // [1000,10000]
    const float* cw  = (const float*)d_in[3];   // [10,10000]
    float* out = (float*)d_out;                 // [32,10]

    char* ws = (char*)d_ws;
    int*       offs  = (int*)(ws + OFFS_OFF);
    uint32_t*  lvl_b = (uint32_t*)(ws + LVL_OFF);
    uint32_t*  pos_b = (uint32_t*)(ws + POS_OFF);
    uint32_t*  part  = (uint32_t*)(ws + PART_OFF);

    k_pack<<<dim3((NL + P) * PACK_BPR), 256, 0, stream>>>(x, lvl, pos, offs, lvl_b, pos_b);
    k_bind<<<dim3(5, CHUNKS, B),         64, 0, stream>>>(offs, lvl_b, pos_b, part);
    k_cls <<<dim3(B),                   320, 0, stream>>>(part, cw, out);
}

// Round 4
// 114.904 us; speedup vs baseline: 1.2178x; 1.1112x over previous
//
#include <hip/hip_runtime.h>
#include <stdint.h>

// Problem constants
#define D    10000   // hypervector dimensions
#define P    784     // pixels
#define B    32      // batch
#define NL   1000    // levels
#define NC   10      // classes

#define ROWW 320           // padded words per packed row (320*32 = 10240 bits >= 10000)
#define ROWB (ROWW * 4)    // 1280 bytes per packed row
#define NW   313           // valid words (ceil(10000/32))
#define CHUNKS 8
#define PLEN  98           // P / CHUNKS
#define PLANES 7           // counts up to 98 < 128

// ws layout (bytes)
#define OFFS_OFF  0
#define LVL_OFF   (B * P * 4)                       // 100352
#define POS_OFF   (LVL_OFF + NL * ROWB)             // +1,280,000
#define PART_OFF  (POS_OFF + P * ROWB)              // (unused now)

#define PACK_BPR 10        // blocks per packed row: 256 thr * 4 dims = 1024; 10*1024 = 10240

// ------- kernel 1: pack sign bits of level & pos (bit=1 means -1) + idx + out-zero --
__global__ void k_pack(const float* __restrict__ x,
                       const float* __restrict__ lvl, const float* __restrict__ pos,
                       int* __restrict__ offs,
                       uint32_t* __restrict__ lvl_b, uint32_t* __restrict__ pos_b,
                       float* __restrict__ out) {
    int bx  = blockIdx.x;
    int row = bx / PACK_BPR;
    int seg = bx % PACK_BPR;
    int d0  = seg * 1024 + threadIdx.x * 4;          // each lane: 4 consecutive dims
    const float* src; uint32_t* dst;
    if (row < NL) { src = lvl + (size_t)row * D;        dst = lvl_b + (size_t)row * ROWW; }
    else          { src = pos + (size_t)(row - NL) * D; dst = pos_b + (size_t)(row - NL) * ROWW; }

    uint32_t nib = 0;
    if (d0 < D) {                                    // D%4==0 -> full float4 or nothing
        float4 v = *(const float4*)(src + d0);
        nib = (v.x < 0.0f ? 1u : 0u) | (v.y < 0.0f ? 2u : 0u) |
              (v.z < 0.0f ? 4u : 0u) | (v.w < 0.0f ? 8u : 0u);
    }
    int lane = threadIdx.x & 63;
    uint32_t val = nib << ((lane & 7) * 4);          // word j <- lanes 8j..8j+7
    val |= __shfl_xor(val, 1, 64);
    val |= __shfl_xor(val, 2, 64);
    val |= __shfl_xor(val, 4, 64);
    if ((lane & 7) == 0) {
        int gword = (seg * 1024 + (threadIdx.x & ~7) * 4) >> 5;
        dst[gword] = val;                            // lanes 0,8,..: consecutive words
    }

    // fused gather-offset computation: B*P = 25088 = 98 blocks * 256 threads
    if (bx < 98) {
        int i = bx * 256 + threadIdx.x;
        float v = rintf(x[i] * 999.0f);              // round-half-even == jnp.round
        v = fminf(fmaxf(v, 0.0f), 999.0f);
        offs[i] = (int)v * ROWB;                     // byte offset of packed level row
    }
    // zero logits (k_bindcls accumulates with atomics; graph orders k_pack first)
    if (bx < 2) {
        int i = bx * 256 + threadIdx.x;
        if (i < B * NC) out[i] = 0.0f;
    }
}

// ------- kernel 2: fused bind (XOR) + bundle (bit-sliced) + sign + classify ---------
template <int N>
__device__ inline void bsadd(const uint32_t* a, const uint32_t* b, uint32_t* s) {
    uint32_t cin = 0;
    #pragma unroll
    for (int k = 0; k < N; k++) {
        uint32_t t = a[k] ^ b[k];
        s[k] = t ^ cin;
        cin  = (a[k] & b[k]) | (cin & t);
    }
    s[N] = cin;
}

// grid = (5 word-segs, B), block = 512 (8 waves; wave w handles pixel chunk w)
__global__ __launch_bounds__(512) void k_bindcls(const int* __restrict__ offs,
                                                 const uint32_t* __restrict__ lvl_b,
                                                 const uint32_t* __restrict__ pos_b,
                                                 const float* __restrict__ cw,
                                                 float* __restrict__ out) {
    int b = blockIdx.y, seg = blockIdx.x;
    int wave = threadIdx.x >> 6, lane = threadIdx.x & 63;
    int gw = seg * 64 + lane;                        // global word [0,320)
    const int* po = offs + b * P + wave * PLEN;      // wave-uniform -> scalar loads
    const uint32_t* pb = pos_b + (size_t)(wave * PLEN) * ROWW + gw;
    const char* lb = (const char*)lvl_b;
    int wb = gw << 2;

    uint32_t pl[PLANES];
    #pragma unroll
    for (int k = 0; k < PLANES; k++) pl[k] = 0;

    #pragma unroll 7
    for (int i = 0; i < PLEN; i += 2) {
        int o0 = po[i], o1 = po[i + 1];
        uint32_t l0 = *(const uint32_t*)(lb + o0 + wb);
        uint32_t l1 = *(const uint32_t*)(lb + o1 + wb);
        uint32_t x0 = l0 ^ pb[(size_t)i * ROWW];
        uint32_t x1 = l1 ^ pb[(size_t)(i + 1) * ROWW];
        uint32_t t  = x0 ^ x1;                       // CSA full-adder into bit-planes
        uint32_t cr = (x0 & x1) | (pl[0] & t);
        pl[0] ^= t;
        #pragma unroll
        for (int k = 1; k < PLANES; k++) { uint32_t tt = pl[k] & cr; pl[k] ^= cr; cr = tt; }
    }

    __shared__ uint32_t red[CHUNKS][PLANES][64];
    #pragma unroll
    for (int k = 0; k < PLANES; k++) red[wave][k][lane] = pl[k];
    __syncthreads();

    __shared__ uint32_t minus_s[64];
    if (wave == 0) {
        uint32_t ch[CHUNKS][PLANES];
        #pragma unroll
        for (int c = 0; c < CHUNKS; c++)
            #pragma unroll
            for (int k = 0; k < PLANES; k++)
                ch[c][k] = red[c][k][lane];

        uint32_t s01[8], s23[8], s45[8], s67[8], t0[9], t1[9], s[10];
        bsadd<7>(ch[0], ch[1], s01);
        bsadd<7>(ch[2], ch[3], s23);
        bsadd<7>(ch[4], ch[5], s45);
        bsadd<7>(ch[6], ch[7], s67);
        bsadd<8>(s01, s23, t0);
        bsadd<8>(s45, s67, t1);
        bsadd<9>(t0, t1, s);
        // minus-mask: S >= 392  (carry-out of S + 632; 632 = bits {3,4,5,6,9})
        minus_s[lane] = s[9] | (s[8] & s[7] & (s[3] | s[4] | s[5] | s[6]));
    }
    __syncthreads();

    // classify: waves 0..4, wave k handles classes 2k, 2k+1
    if (wave < 5) {
        uint32_t minus = minus_s[lane];
        float sgn[32];
        #pragma unroll
        for (int j = 0; j < 32; j++) sgn[j] = ((minus >> j) & 1u) ? -1.0f : 1.0f;

        float a0 = 0.0f, a1 = 0.0f;
        int c0 = wave * 2;
        const float* r0 = cw + (size_t)c0 * D + gw * 32;
        const float* r1 = r0 + D;
        if (gw < NW - 1) {
            #pragma unroll
            for (int j = 0; j < 32; j++) { a0 = fmaf(sgn[j], r0[j], a0); a1 = fmaf(sgn[j], r1[j], a1); }
        } else if (gw == NW - 1) {                   // word 312: dims 9984..9999
            #pragma unroll
            for (int j = 0; j < 16; j++) { a0 = fmaf(sgn[j], r0[j], a0); a1 = fmaf(sgn[j], r1[j], a1); }
        }
        for (int o = 32; o > 0; o >>= 1) { a0 += __shfl_down(a0, o, 64); a1 += __shfl_down(a1, o, 64); }
        if (lane == 0) {
            atomicAdd(out + b * NC + c0,     a0);
            atomicAdd(out + b * NC + c0 + 1, a1);
        }
    }
}

extern "C" void kernel_launch(void* const* d_in, const int* in_sizes, int n_in,
                              void* d_out, int out_size, void* d_ws, size_t ws_size,
                              hipStream_t stream) {
    const float* x   = (const float*)d_in[0];   // [32,1,28,28]
    const float* pos = (const float*)d_in[1];   // [784,10000]
    const float* lvl = (const float*)d_in[2];   // [1000,10000]
    const float* cw  = (const float*)d_in[3];   // [10,10000]
    float* out = (float*)d_out;                 // [32,10]

    char* ws = (char*)d_ws;
    int*       offs  = (int*)(ws + OFFS_OFF);
    uint32_t*  lvl_b = (uint32_t*)(ws + LVL_OFF);
    uint32_t*  pos_b = (uint32_t*)(ws + POS_OFF);

    k_pack   <<<dim3((NL + P) * PACK_BPR), 256, 0, stream>>>(x, lvl, pos, offs, lvl_b, pos_b, out);
    k_bindcls<<<dim3(5, B),                512, 0, stream>>>(offs, lvl_b, pos_b, cw, out);
}